// Round 16
// baseline (162.758 us; speedup 1.0000x reference)
//
#include <hip/hip_runtime.h>
#include <math.h>

#define NQ   12
#define NL   4
#define NT   256   // 4 waves = 2 independent samples x 2 waves
#define AMPS 32    // per-thread amplitudes
// Per sample: 128 threads (ltid = tid & 127). state bit 11 = ltid bit 6 (wave-in-sample),
// bits 10..5 = lane bits 5..0 (wires 1..6), bits 4..0 = j bits 4..0 (wires 7..11)

typedef float cplx __attribute__((ext_vector_type(2)));   // VGPR pair for VOP3P

// ---- fused complex pair-op: u = Mx*s + My*p, exactly 4 VOP3P instrs (R10-validated)
__device__ __forceinline__ cplx cpair(cplx Mx, cplx s, cplx My, cplx p) {
    cplx u;
    asm("v_pk_mul_f32 %0, %1, %2 op_sel:[0,0] op_sel_hi:[0,1]\n\t"
        "v_pk_fma_f32 %0, %1, %2, %0 op_sel:[1,1,0] op_sel_hi:[1,0,1] neg_lo:[1,0,0]\n\t"
        "v_pk_fma_f32 %0, %3, %4, %0 op_sel:[0,0,0] op_sel_hi:[0,1,1]\n\t"
        "v_pk_fma_f32 %0, %3, %4, %0 op_sel:[1,1,0] op_sel_hi:[1,0,1] neg_lo:[1,0,0]"
        : "=&v"(u) : "v"(Mx), "v"(s), "v"(My), "v"(p));
    return u;
}
// u = a*b (complex), 2 instrs (R9-validated)
__device__ __forceinline__ cplx pk_cmul(cplx a, cplx b) {
    cplx u;
    asm("v_pk_mul_f32 %0, %1, %2 op_sel:[0,0] op_sel_hi:[0,1]\n\t"
        "v_pk_fma_f32 %0, %1, %2, %0 op_sel:[1,1,0] op_sel_hi:[1,0,1] neg_lo:[1,0,0]"
        : "=&v"(u) : "v"(a), "v"(b));
    return u;
}

// C = A * B (2x2 complex, row-major m00 m01 m10 m11)
__device__ __forceinline__ void mm2(const cplx* A, const cplx* B, cplx* C) {
    C[0] = cpair(A[0], B[0], A[1], B[2]);
    C[1] = cpair(A[0], B[1], A[1], B[3]);
    C[2] = cpair(A[2], B[0], A[3], B[2]);
    C[3] = cpair(A[2], B[1], A[3], B[3]);
}
// PennyLane Rot(phi, theta, omega) = RZ(omega) RY(theta) RZ(phi)
__device__ __forceinline__ void rotmat(float phi, float th, float om, cplx* M) {
    float ct, st_, ca, sa, cd, sd;
    sincosf(0.5f * th, &st_, &ct);
    sincosf(0.5f * (phi + om), &sa, &ca);
    sincosf(0.5f * (phi - om), &sd, &cd);
    M[0] = cplx{ct * ca, -ct * sa};
    M[1] = cplx{-st_ * cd, -st_ * sd};
    M[2] = cplx{st_ * cd, -st_ * sd};
    M[3] = cplx{ct * ca, ct * sa};
}
__device__ __forceinline__ void rowsel(const cplx* M, bool hi, cplx& Mx, cplx& My) {
    Mx = hi ? M[3] : M[0];
    My = hi ? M[2] : M[1];
}

// ---- cross-lane partner fetch for xor mask XM (all primitives R9/R10-validated)
// xor1/2: DPP quad_perm. xor8: row_ror:8. xor4/16/32: __shfl_xor (DS pipe).
template<int CTRL>
__device__ __forceinline__ float dpp_perm(float v) {
    return __int_as_float(__builtin_amdgcn_update_dpp(
        __float_as_int(v), __float_as_int(v), CTRL, 0xF, 0xF, false));
}
template<int XM>
__device__ __forceinline__ float partner(float v) {
    if constexpr (XM == 8)      return dpp_perm<0x128>(v);   // row_ror:8
    else if constexpr (XM == 2) return dpp_perm<0x4E>(v);    // quad_perm [2,3,0,1]
    else if constexpr (XM == 1) return dpp_perm<0xB1>(v);    // quad_perm [1,0,3,2]
    else                        return __shfl_xor(v, XM, 64);
}

// gate on a LANE target bit (xor mask XM); per-thread (Mx,My) pre-selected.
template<int XM>
__device__ __forceinline__ void lane_gate(cplx* s, cplx Mx, cplx My) {
    #pragma unroll
    for (int j0 = 0; j0 < AMPS; j0 += 4) {
        cplx pv[4];
        #pragma unroll
        for (int j = 0; j < 4; ++j) {
            pv[j].x = partner<XM>(s[j0 + j].x);
            pv[j].y = partner<XM>(s[j0 + j].y);
        }
        #pragma unroll
        for (int j = 0; j < 4; ++j)
            s[j0 + j] = cpair(Mx, s[j0 + j], My, pv[j]);
    }
}
// full 2x2 gate on LOCAL bit K, uniform matrix (per-thread)
template<int K>
__device__ __forceinline__ void local_gate(cplx* s, cplx M0, cplx M1, cplx M2, cplx M3) {
    #pragma unroll
    for (int j = 0; j < AMPS; ++j) {
        if ((j >> K) & 1) continue;
        const int i1 = j | (1 << K);
        cplx v0 = s[j], v1 = s[i1];
        s[j]  = cpair(M0, v0, M1, v1);
        s[i1] = cpair(M2, v0, M3, v1);
    }
}
// controlled pair-gate: control LOCAL bit CB selects A (c=0) or B (c=1), target LOCAL bit TB
template<int CB, int TB>
__device__ __forceinline__ void cgate_local(cplx* s, const cplx* A, const cplx* B) {
    cplx A0 = A[0], A1 = A[1], A2 = A[2], A3 = A[3];
    cplx B0 = B[0], B1 = B[1], B2 = B[2], B3 = B[3];
    #pragma unroll
    for (int j = 0; j < AMPS; ++j) {
        if ((j >> TB) & 1) continue;
        const int i1 = j | (1 << TB);
        cplx v0 = s[j], v1 = s[i1];
        if ((j >> CB) & 1) {
            s[j]  = cpair(B0, v0, B1, v1);
            s[i1] = cpair(B2, v0, B3, v1);
        } else {
            s[j]  = cpair(A0, v0, A1, v1);
            s[i1] = cpair(A2, v0, A3, v1);
        }
    }
}

__global__ __launch_bounds__(NT, 2) void qsim_kernel(
    const float* __restrict__ x,      // (B, 4, NQ)
    const float* __restrict__ prot,   // (NL, NQ, 3)
    const float* __restrict__ penta,  // (NL, NQ, 3)
    float* __restrict__ out)          // (B, NQ)
{
    // Per-SAMPLE LDS slices (2 samples per block).
    __shared__ cplx xbufA[2][1024];     // setup scratch + q11 exchange buffer (8 KB each)
    __shared__ cplx GAA[2][NL * NQ][4]; // c=0 branch (persistent)
    __shared__ cplx GBA[2][NL * NQ][4]; // c=1 branch (persistent)
    __shared__ cplx ltabA[2][AMPS];     // layer-0 product over wires 7..11
    __shared__ float zredA[2][2][NQ];

    const int tid  = threadIdx.x;
    const int st   = tid >> 7;          // sample within block (0/1)
    const int ltid = tid & 127;         // thread id within sample
    const int lane = tid & 63;
    const int w    = (tid >> 6) & 1;    // wave within sample = state bit 11 = wire 0
    const int b    = blockIdx.x * 2 + st;

    cplx* xb   = &xbufA[st][0];
    cplx* ENCp = xb;                    // 48
    cplx* RMp  = xb + 48;               // 192
    cplx* EMp  = xb + 240;              // 192
    cplx* UUp  = xb + 432;              // 192 (ends at 624 < 1024)
    cplx (*GA)[4] = GAA[st];
    cplx (*GB)[4] = GBA[st];
    cplx* ltab = ltabA[st];

    // ---- per-sample fused encoding: ENC = RY(x3) RZ(x2) RX(x1) RY(x0)
    if (ltid < NQ) {
        const int q = ltid;
        const float* xbp = x + (size_t)b * 4 * NQ;
        const float t0 = xbp[q], t1 = xbp[NQ + q], t2 = xbp[2 * NQ + q], t3 = xbp[3 * NQ + q];
        float c, s;
        sincosf(0.5f * t0, &s, &c);
        cplx R0[4] = {cplx{c, 0.f}, cplx{-s, 0.f}, cplx{s, 0.f}, cplx{c, 0.f}};   // RY
        sincosf(0.5f * t1, &s, &c);
        cplx R1[4] = {cplx{c, 0.f}, cplx{0.f, -s}, cplx{0.f, -s}, cplx{c, 0.f}};  // RX
        sincosf(0.5f * t2, &s, &c);
        cplx R2[4] = {cplx{c, -s}, cplx{0.f, 0.f}, cplx{0.f, 0.f}, cplx{c, s}};   // RZ
        sincosf(0.5f * t3, &s, &c);
        cplx R3[4] = {cplx{c, 0.f}, cplx{-s, 0.f}, cplx{s, 0.f}, cplx{c, 0.f}};   // RY
        cplx T1[4], T2[4], E[4];
        mm2(R1, R0, T1);
        mm2(R2, T1, T2);
        mm2(R3, T2, E);
        #pragma unroll
        for (int i = 0; i < 4; ++i) ENCp[q * 4 + i] = E[i];
    }
    if (ltid < NL * NQ) {
        cplx M[4];
        rotmat(prot[3 * ltid], prot[3 * ltid + 1], prot[3 * ltid + 2], M);
        #pragma unroll
        for (int i = 0; i < 4; ++i) RMp[ltid * 4 + i] = M[i];
        rotmat(penta[3 * ltid], penta[3 * ltid + 1], penta[3 * ltid + 2], M);
        #pragma unroll
        for (int i = 0; i < 4; ++i) EMp[ltid * 4 + i] = M[i];
    }
    __syncthreads();
    if (ltid < NL * NQ) {
        cplx U[4];
        mm2(RMp + ltid * 4, ENCp + (ltid % NQ) * 4, U);
        #pragma unroll
        for (int i = 0; i < 4; ++i) UUp[ltid * 4 + i] = U[i];
    }
    __syncthreads();
    // ---- fused controlled-gate pairs (validated rounds 3-11):
    // q<11:  A = U_{q+1}(l) (I for l=0), B = EM * A
    // q==11: A = U_0(l+1)   (I for l=3), B = A * EM
    if (ltid < NL * NQ) {
        const int l = ltid / NQ, q = ltid - l * NQ;
        cplx A[4], B[4];
        if (q < 11) {
            if (l == 0) { A[0] = cplx{1.f,0.f}; A[1] = cplx{0.f,0.f}; A[2] = cplx{0.f,0.f}; A[3] = cplx{1.f,0.f}; }
            else {
                #pragma unroll
                for (int i = 0; i < 4; ++i) A[i] = UUp[(l * NQ + q + 1) * 4 + i];
            }
            mm2(EMp + ltid * 4, A, B);
        } else {
            if (l == NL - 1) { A[0] = cplx{1.f,0.f}; A[1] = cplx{0.f,0.f}; A[2] = cplx{0.f,0.f}; A[3] = cplx{1.f,0.f}; }
            else {
                #pragma unroll
                for (int i = 0; i < 4; ++i) A[i] = UUp[((l + 1) * NQ) * 4 + i];
            }
            mm2(A, EMp + ltid * 4, B);
        }
        #pragma unroll
        for (int i = 0; i < 4; ++i) { GA[ltid][i] = A[i]; GB[ltid][i] = B[i]; }
    }
    // ---- layer-0 local-wire product table (wires 7..11 -> j bits 4..0)
    if (ltid >= 64 && ltid < 64 + AMPS) {
        const int j = ltid - 64;
        cplx m = cplx{1.f, 0.f};
        #pragma unroll
        for (int wq = 7; wq < 12; ++wq) {
            const int bit = (j >> (11 - wq)) & 1;
            m = pk_cmul(m, bit ? UUp[wq * 4 + 2] : UUp[wq * 4 + 0]);
        }
        ltab[j] = m;
    }
    // ---- per-thread lane prefix from layer-0 1q gates (wires 0..6 -> ltid bits 6..0)
    cplx lp = cplx{1.f, 0.f};
    #pragma unroll
    for (int wq = 0; wq < 7; ++wq) {
        const int bit = (ltid >> (6 - wq)) & 1;
        lp = pk_cmul(lp, bit ? UUp[wq * 4 + 2] : UUp[wq * 4 + 0]);
    }
    __syncthreads();

    // ---- init: product state
    cplx s[AMPS];
    #pragma unroll
    for (int j = 0; j < AMPS; ++j) s[j] = pk_cmul(lp, ltab[j]);

    // ---- 48 fused controlled-pair gates
    for (int l = 0; l < NL; ++l) {
        const int g = l * NQ;
        // q=0: c wire0 (wave bit), t wire1 = lane bit5 (xor 32)
        {
            const cplx* M = w ? &GB[g + 0][0] : &GA[g + 0][0];
            cplx Mx, My; rowsel(M, ltid & 32, Mx, My);
            lane_gate<32>(s, Mx, My);
        }
        // q=1: c lane5, t lane4 (xor 16)
        {
            const cplx* M = (ltid & 32) ? &GB[g + 1][0] : &GA[g + 1][0];
            cplx Mx, My; rowsel(M, ltid & 16, Mx, My);
            lane_gate<16>(s, Mx, My);
        }
        // q=2: c lane4, t lane3 (xor 8, DPP)
        {
            const cplx* M = (ltid & 16) ? &GB[g + 2][0] : &GA[g + 2][0];
            cplx Mx, My; rowsel(M, ltid & 8, Mx, My);
            lane_gate<8>(s, Mx, My);
        }
        // q=3: c lane3, t lane2 (xor 4)
        {
            const cplx* M = (ltid & 8) ? &GB[g + 3][0] : &GA[g + 3][0];
            cplx Mx, My; rowsel(M, ltid & 4, Mx, My);
            lane_gate<4>(s, Mx, My);
        }
        // q=4: c lane2, t lane1 (xor 2, DPP)
        {
            const cplx* M = (ltid & 4) ? &GB[g + 4][0] : &GA[g + 4][0];
            cplx Mx, My; rowsel(M, ltid & 2, Mx, My);
            lane_gate<2>(s, Mx, My);
        }
        // q=5: c lane1, t lane0 (xor 1, DPP)
        {
            const cplx* M = (ltid & 2) ? &GB[g + 5][0] : &GA[g + 5][0];
            cplx Mx, My; rowsel(M, ltid & 1, Mx, My);
            lane_gate<1>(s, Mx, My);
        }
        // q=6: c lane0, t local bit4
        {
            const cplx* M = (ltid & 1) ? &GB[g + 6][0] : &GA[g + 6][0];
            local_gate<4>(s, M[0], M[1], M[2], M[3]);
        }
        // q=7..10: both local
        cgate_local<4, 3>(s, &GA[g + 7][0], &GB[g + 7][0]);
        cgate_local<3, 2>(s, &GA[g + 8][0], &GB[g + 8][0]);
        cgate_local<2, 1>(s, &GA[g + 9][0], &GB[g + 9][0]);
        cgate_local<1, 0>(s, &GA[g + 10][0], &GB[g + 10][0]);
        // q=11: c local bit0 (j parity), t wire0 = wave bit -> per-sample LDS exchange ltid^64
        // 4 rounds x 8 amps, packed as float4 pairs (even amp -> A, odd -> B)
        {
            cplx Ax, Ay, Bx, By;
            rowsel(&GA[g + 11][0], w, Ax, Ay);
            rowsel(&GB[g + 11][0], w, Bx, By);
            float4* xb4 = (float4*)xb;
            #pragma unroll
            for (int r = 0; r < 4; ++r) {
                __syncthreads();
                #pragma unroll
                for (int j2 = 0; j2 < 4; ++j2) {
                    const int j = r * 8 + 2 * j2;
                    xb4[j2 * 128 + ltid] = make_float4(s[j].x, s[j].y, s[j + 1].x, s[j + 1].y);
                }
                __syncthreads();
                #pragma unroll
                for (int j2 = 0; j2 < 4; ++j2) {
                    float4 f = xb4[j2 * 128 + (ltid ^ 64)];
                    const int j = r * 8 + 2 * j2;
                    s[j]     = cpair(Ax, s[j],     Ay, cplx{f.x, f.y});
                    s[j + 1] = cpair(Bx, s[j + 1], By, cplx{f.z, f.w});
                }
            }
        }
    }

    // ---- measurement: z_i over state bit (11-i); amp = (ltid<<5)|j
    float psum = 0.f;
    float zl0 = 0.f, zl1 = 0.f, zl2 = 0.f, zl3 = 0.f, zl4 = 0.f;  // wires 7..11
    #pragma unroll
    for (int j = 0; j < AMPS; ++j) {
        cplx v = s[j];
        float pr = fmaf(v.x, v.x, v.y * v.y);
        psum += pr;
        int pb = __float_as_int(pr);
        zl0 += __int_as_float(pb ^ (((j >> 4) & 1) << 31));
        zl1 += __int_as_float(pb ^ (((j >> 3) & 1) << 31));
        zl2 += __int_as_float(pb ^ (((j >> 2) & 1) << 31));
        zl3 += __int_as_float(pb ^ (((j >> 1) & 1) << 31));
        zl4 += __int_as_float(pb ^ ((j & 1) << 31));
    }
    float zv[NQ];
    #pragma unroll
    for (int i = 0; i < 7; ++i)                       // wires 0..6: sign = ltid bit (6-i)
        zv[i] = ((ltid >> (6 - i)) & 1) ? -psum : psum;
    zv[7] = zl0; zv[8] = zl1; zv[9] = zl2; zv[10] = zl3; zv[11] = zl4;
    #pragma unroll
    for (int q = 0; q < NQ; ++q) {
        float v = zv[q];
        #pragma unroll
        for (int off = 32; off > 0; off >>= 1) v += __shfl_xor(v, off, 64);
        zv[q] = v;
    }
    if (lane == 0) {
        #pragma unroll
        for (int q = 0; q < NQ; ++q) zredA[st][w][q] = zv[q];
    }
    __syncthreads();
    if (ltid < NQ)
        out[(size_t)b * NQ + ltid] = zredA[st][0][ltid] + zredA[st][1][ltid];
}

extern "C" void kernel_launch(void* const* d_in, const int* in_sizes, int n_in,
                              void* d_out, int out_size, void* d_ws, size_t ws_size,
                              hipStream_t stream) {
    const float* x     = (const float*)d_in[0];
    const float* prot  = (const float*)d_in[1];
    const float* penta = (const float*)d_in[2];
    float* out = (float*)d_out;
    const int B = in_sizes[0] / (4 * NQ);   // 4096
    qsim_kernel<<<B / 2, NT, 0, stream>>>(x, prot, penta, out);
}

// Round 17
// 159.629 us; speedup vs baseline: 1.0196x; 1.0196x over previous
//
#include <hip/hip_runtime.h>
#include <math.h>

#define NQ   12
#define NL   4
#define NT   64
#define AMPS 64   // per-thread amplitudes; amp = (lane<<6) | j
// state bits 11..6 = lane bits 5..0 (wires 0..5); state bits 5..0 = j bits 5..0 (wires 6..11)

typedef float cplx __attribute__((ext_vector_type(2)));   // VGPR pair for VOP3P

// ---- complex pair-op u = Mx*s + My*p as FOUR single-instruction asm blocks.
// Identical instructions/dataflow to the R10/R11-validated fused block, but each
// instruction is its own (non-volatile) asm unit so LLVM can interleave
// independent amp-chains and hide the ~4-cycle VALU dependency latency.
__device__ __forceinline__ cplx cpair(cplx Mx, cplx s, cplx My, cplx p) {
    cplx u;
    asm("v_pk_mul_f32 %0, %1, %2 op_sel:[0,0] op_sel_hi:[0,1]"
        : "=v"(u) : "v"(Mx), "v"(s));
    asm("v_pk_fma_f32 %0, %1, %2, %0 op_sel:[1,1,0] op_sel_hi:[1,0,1] neg_lo:[1,0,0]"
        : "+v"(u) : "v"(Mx), "v"(s));
    asm("v_pk_fma_f32 %0, %1, %2, %0 op_sel:[0,0,0] op_sel_hi:[0,1,1]"
        : "+v"(u) : "v"(My), "v"(p));
    asm("v_pk_fma_f32 %0, %1, %2, %0 op_sel:[1,1,0] op_sel_hi:[1,0,1] neg_lo:[1,0,0]"
        : "+v"(u) : "v"(My), "v"(p));
    return u;
}
// u = a*b (complex), 2 single-instruction blocks (R9-validated encodings)
__device__ __forceinline__ cplx pk_cmul(cplx a, cplx b) {
    cplx u;
    asm("v_pk_mul_f32 %0, %1, %2 op_sel:[0,0] op_sel_hi:[0,1]"
        : "=v"(u) : "v"(a), "v"(b));
    asm("v_pk_fma_f32 %0, %1, %2, %0 op_sel:[1,1,0] op_sel_hi:[1,0,1] neg_lo:[1,0,0]"
        : "+v"(u) : "v"(a), "v"(b));
    return u;
}

// C = A * B (2x2 complex, row-major m00 m01 m10 m11)
__device__ __forceinline__ void mm2(const cplx* A, const cplx* B, cplx* C) {
    C[0] = cpair(A[0], B[0], A[1], B[2]);
    C[1] = cpair(A[0], B[1], A[1], B[3]);
    C[2] = cpair(A[2], B[0], A[3], B[2]);
    C[3] = cpair(A[2], B[1], A[3], B[3]);
}
// PennyLane Rot(phi, theta, omega) = RZ(omega) RY(theta) RZ(phi)
__device__ __forceinline__ void rotmat(float phi, float th, float om, cplx* M) {
    float ct, st_, ca, sa, cd, sd;
    sincosf(0.5f * th, &st_, &ct);
    sincosf(0.5f * (phi + om), &sa, &ca);
    sincosf(0.5f * (phi - om), &sd, &cd);
    M[0] = cplx{ct * ca, -ct * sa};
    M[1] = cplx{-st_ * cd, -st_ * sd};
    M[2] = cplx{st_ * cd, -st_ * sd};
    M[3] = cplx{ct * ca, ct * sa};
}
__device__ __forceinline__ void rowsel(const cplx* M, bool hi, cplx& Mx, cplx& My) {
    Mx = hi ? M[3] : M[0];
    My = hi ? M[2] : M[1];
}

// ---- cross-lane partner fetch for xor mask XM (all primitives R9/R10/R11-validated)
// xor1/2: DPP quad_perm. xor8: row_ror:8. xor4/16/32: __shfl_xor (DS pipe).
template<int CTRL>
__device__ __forceinline__ float dpp_perm(float v) {
    return __int_as_float(__builtin_amdgcn_update_dpp(
        __float_as_int(v), __float_as_int(v), CTRL, 0xF, 0xF, false));
}
template<int XM>
__device__ __forceinline__ float partner(float v) {
    if constexpr (XM == 8)      return dpp_perm<0x128>(v);   // row_ror:8
    else if constexpr (XM == 2) return dpp_perm<0x4E>(v);    // quad_perm [2,3,0,1]
    else if constexpr (XM == 1) return dpp_perm<0xB1>(v);    // quad_perm [1,0,3,2]
    else                        return __shfl_xor(v, XM, 64);
}

// gate on a LANE target bit (xor mask XM); per-thread (Mx,My) pre-selected.
template<int XM>
__device__ __forceinline__ void lane_gate(cplx* s, cplx Mx, cplx My) {
    #pragma unroll
    for (int j0 = 0; j0 < AMPS; j0 += 4) {
        cplx pv[4];
        #pragma unroll
        for (int j = 0; j < 4; ++j) {
            pv[j].x = partner<XM>(s[j0 + j].x);
            pv[j].y = partner<XM>(s[j0 + j].y);
        }
        #pragma unroll
        for (int j = 0; j < 4; ++j)
            s[j0 + j] = cpair(Mx, s[j0 + j], My, pv[j]);
    }
}
// full 2x2 gate on LOCAL bit K, uniform matrix (per-thread)
template<int K>
__device__ __forceinline__ void local_gate(cplx* s, cplx M0, cplx M1, cplx M2, cplx M3) {
    #pragma unroll
    for (int j = 0; j < AMPS; ++j) {
        if ((j >> K) & 1) continue;
        const int i1 = j | (1 << K);
        cplx v0 = s[j], v1 = s[i1];
        s[j]  = cpair(M0, v0, M1, v1);
        s[i1] = cpair(M2, v0, M3, v1);
    }
}
// controlled pair-gate: control LOCAL bit CB selects A (c=0) or B (c=1), target LOCAL bit TB
template<int CB, int TB>
__device__ __forceinline__ void cgate_local(cplx* s, const cplx* A, const cplx* B) {
    cplx A0 = A[0], A1 = A[1], A2 = A[2], A3 = A[3];
    cplx B0 = B[0], B1 = B[1], B2 = B[2], B3 = B[3];
    #pragma unroll
    for (int j = 0; j < AMPS; ++j) {
        if ((j >> TB) & 1) continue;
        const int i1 = j | (1 << TB);
        cplx v0 = s[j], v1 = s[i1];
        if ((j >> CB) & 1) {
            s[j]  = cpair(B0, v0, B1, v1);
            s[i1] = cpair(B2, v0, B3, v1);
        } else {
            s[j]  = cpair(A0, v0, A1, v1);
            s[i1] = cpair(A2, v0, A3, v1);
        }
    }
}

__global__ __launch_bounds__(NT, 1) void qsim_kernel(
    const float* __restrict__ x,      // (B, 4, NQ)
    const float* __restrict__ prot,   // (NL, NQ, 3)
    const float* __restrict__ penta,  // (NL, NQ, 3)
    float* __restrict__ out)          // (B, NQ)
{
    __shared__ cplx xbuf[640];        // setup scratch: ENC/RM/EM/UU
    __shared__ cplx GA[NL * NQ][4];   // c=0 branch (persistent)
    __shared__ cplx GB[NL * NQ][4];   // c=1 branch (persistent)
    __shared__ cplx ltab[AMPS];       // layer-0 product over wires 6..11

    cplx* ENCp = xbuf;                // 48
    cplx* RMp  = xbuf + 48;           // 192
    cplx* EMp  = xbuf + 240;          // 192
    cplx* UUp  = xbuf + 432;          // 192 (ends at 624)

    const int tid = threadIdx.x;      // == lane, 0..63
    const int b   = blockIdx.x;

    // ---- per-sample fused encoding: ENC = RY(x3) RZ(x2) RX(x1) RY(x0)
    if (tid < NQ) {
        const int q = tid;
        const float* xb = x + (size_t)b * 4 * NQ;
        const float t0 = xb[q], t1 = xb[NQ + q], t2 = xb[2 * NQ + q], t3 = xb[3 * NQ + q];
        float c, s;
        sincosf(0.5f * t0, &s, &c);
        cplx R0[4] = {cplx{c, 0.f}, cplx{-s, 0.f}, cplx{s, 0.f}, cplx{c, 0.f}};   // RY
        sincosf(0.5f * t1, &s, &c);
        cplx R1[4] = {cplx{c, 0.f}, cplx{0.f, -s}, cplx{0.f, -s}, cplx{c, 0.f}};  // RX
        sincosf(0.5f * t2, &s, &c);
        cplx R2[4] = {cplx{c, -s}, cplx{0.f, 0.f}, cplx{0.f, 0.f}, cplx{c, s}};   // RZ
        sincosf(0.5f * t3, &s, &c);
        cplx R3[4] = {cplx{c, 0.f}, cplx{-s, 0.f}, cplx{s, 0.f}, cplx{c, 0.f}};   // RY
        cplx T1[4], T2[4], E[4];
        mm2(R1, R0, T1);
        mm2(R2, T1, T2);
        mm2(R3, T2, E);
        #pragma unroll
        for (int i = 0; i < 4; ++i) ENCp[q * 4 + i] = E[i];
    }
    if (tid < NL * NQ) {
        cplx M[4];
        rotmat(prot[3 * tid], prot[3 * tid + 1], prot[3 * tid + 2], M);
        #pragma unroll
        for (int i = 0; i < 4; ++i) RMp[tid * 4 + i] = M[i];
        rotmat(penta[3 * tid], penta[3 * tid + 1], penta[3 * tid + 2], M);
        #pragma unroll
        for (int i = 0; i < 4; ++i) EMp[tid * 4 + i] = M[i];
    }
    __syncthreads();
    if (tid < NL * NQ) {
        cplx U[4];
        mm2(RMp + tid * 4, ENCp + (tid % NQ) * 4, U);
        #pragma unroll
        for (int i = 0; i < 4; ++i) UUp[tid * 4 + i] = U[i];
    }
    __syncthreads();
    // ---- fused controlled-gate pairs (validated rounds 3-11):
    // q<11:  A = U_{q+1}(l) (I for l=0), B = EM * A
    // q==11: A = U_0(l+1)   (I for l=3), B = A * EM
    if (tid < NL * NQ) {
        const int l = tid / NQ, q = tid - l * NQ;
        cplx A[4], B[4];
        if (q < 11) {
            if (l == 0) { A[0] = cplx{1.f,0.f}; A[1] = cplx{0.f,0.f}; A[2] = cplx{0.f,0.f}; A[3] = cplx{1.f,0.f}; }
            else {
                #pragma unroll
                for (int i = 0; i < 4; ++i) A[i] = UUp[(l * NQ + q + 1) * 4 + i];
            }
            mm2(EMp + tid * 4, A, B);
        } else {
            if (l == NL - 1) { A[0] = cplx{1.f,0.f}; A[1] = cplx{0.f,0.f}; A[2] = cplx{0.f,0.f}; A[3] = cplx{1.f,0.f}; }
            else {
                #pragma unroll
                for (int i = 0; i < 4; ++i) A[i] = UUp[((l + 1) * NQ) * 4 + i];
            }
            mm2(A, EMp + tid * 4, B);
        }
        #pragma unroll
        for (int i = 0; i < 4; ++i) { GA[tid][i] = A[i]; GB[tid][i] = B[i]; }
    }
    // ---- layer-0 local-wire product table (wires 6..11 -> j bits 5..0), one entry per thread
    {
        cplx m = cplx{1.f, 0.f};
        #pragma unroll
        for (int wq = 6; wq < 12; ++wq) {
            const int bit = (tid >> (11 - wq)) & 1;
            m = pk_cmul(m, bit ? UUp[wq * 4 + 2] : UUp[wq * 4 + 0]);
        }
        ltab[tid] = m;
    }
    // ---- per-thread lane prefix from layer-0 1q gates on wires 0..5 (lane bits 5..0)
    cplx lp = cplx{1.f, 0.f};
    #pragma unroll
    for (int wq = 0; wq < 6; ++wq) {
        const int bit = (tid >> (5 - wq)) & 1;
        lp = pk_cmul(lp, bit ? UUp[wq * 4 + 2] : UUp[wq * 4 + 0]);
    }
    __syncthreads();

    // ---- init: product state
    cplx s[AMPS];
    #pragma unroll
    for (int j = 0; j < AMPS; ++j) s[j] = pk_cmul(lp, ltab[j]);

    // ---- 48 fused controlled-pair gates, ZERO barriers, zero LDS exchange
    for (int l = 0; l < NL; ++l) {
        const int g = l * NQ;
        // q=0: c wire0 (lane bit5), t wire1 (lane bit4, xor16)
        {
            const cplx* M = (tid & 32) ? &GB[g + 0][0] : &GA[g + 0][0];
            cplx Mx, My; rowsel(M, tid & 16, Mx, My);
            lane_gate<16>(s, Mx, My);
        }
        // q=1: c lane4, t lane3 (xor8, DPP)
        {
            const cplx* M = (tid & 16) ? &GB[g + 1][0] : &GA[g + 1][0];
            cplx Mx, My; rowsel(M, tid & 8, Mx, My);
            lane_gate<8>(s, Mx, My);
        }
        // q=2: c lane3, t lane2 (xor4)
        {
            const cplx* M = (tid & 8) ? &GB[g + 2][0] : &GA[g + 2][0];
            cplx Mx, My; rowsel(M, tid & 4, Mx, My);
            lane_gate<4>(s, Mx, My);
        }
        // q=3: c lane2, t lane1 (xor2, DPP)
        {
            const cplx* M = (tid & 4) ? &GB[g + 3][0] : &GA[g + 3][0];
            cplx Mx, My; rowsel(M, tid & 2, Mx, My);
            lane_gate<2>(s, Mx, My);
        }
        // q=4: c lane1, t lane0 (xor1, DPP)
        {
            const cplx* M = (tid & 2) ? &GB[g + 4][0] : &GA[g + 4][0];
            cplx Mx, My; rowsel(M, tid & 1, Mx, My);
            lane_gate<1>(s, Mx, My);
        }
        // q=5: c lane0, t local bit5
        {
            const cplx* M = (tid & 1) ? &GB[g + 5][0] : &GA[g + 5][0];
            local_gate<5>(s, M[0], M[1], M[2], M[3]);
        }
        // q=6..10: both local
        cgate_local<5, 4>(s, &GA[g + 6][0], &GB[g + 6][0]);
        cgate_local<4, 3>(s, &GA[g + 7][0], &GB[g + 7][0]);
        cgate_local<3, 2>(s, &GA[g + 8][0], &GB[g + 8][0]);
        cgate_local<2, 1>(s, &GA[g + 9][0], &GB[g + 9][0]);
        cgate_local<1, 0>(s, &GA[g + 10][0], &GB[g + 10][0]);
        // q=11: c local bit0 (j parity), t wire0 (lane bit5) -> xor32 shuffle, per-amp A/B
        {
            cplx Ax, Ay, Bx, By;
            rowsel(&GA[g + 11][0], tid & 32, Ax, Ay);
            rowsel(&GB[g + 11][0], tid & 32, Bx, By);
            #pragma unroll
            for (int j0 = 0; j0 < AMPS; j0 += 4) {
                cplx pv[4];
                #pragma unroll
                for (int j = 0; j < 4; ++j) {
                    pv[j].x = __shfl_xor(s[j0 + j].x, 32, 64);
                    pv[j].y = __shfl_xor(s[j0 + j].y, 32, 64);
                }
                #pragma unroll
                for (int j = 0; j < 4; ++j) {
                    if ((j0 + j) & 1) s[j0 + j] = cpair(Bx, s[j0 + j], By, pv[j]);
                    else              s[j0 + j] = cpair(Ax, s[j0 + j], Ay, pv[j]);
                }
            }
        }
    }

    // ---- measurement: z_i over state bit (11-i); amp = (tid<<6)|j
    float psum = 0.f;
    float zl[6] = {0.f, 0.f, 0.f, 0.f, 0.f, 0.f};   // wires 6..11 (j bits 5..0)
    #pragma unroll
    for (int j = 0; j < AMPS; ++j) {
        cplx v = s[j];
        float pr = fmaf(v.x, v.x, v.y * v.y);
        psum += pr;
        int pb = __float_as_int(pr);
        #pragma unroll
        for (int i = 0; i < 6; ++i)
            zl[i] += __int_as_float(pb ^ (((j >> (5 - i)) & 1) << 31));
    }
    float zv[NQ];
    #pragma unroll
    for (int i = 0; i < 6; ++i)                      // wires 0..5: sign = lane bit (5-i)
        zv[i] = ((tid >> (5 - i)) & 1) ? -psum : psum;
    #pragma unroll
    for (int i = 0; i < 6; ++i) zv[6 + i] = zl[i];
    #pragma unroll
    for (int q = 0; q < NQ; ++q) {
        float v = zv[q];
        #pragma unroll
        for (int off = 32; off > 0; off >>= 1) v += __shfl_xor(v, off, 64);
        zv[q] = v;
    }
    if (tid == 0) {
        float* ob = out + (size_t)b * NQ;
        #pragma unroll
        for (int q = 0; q < NQ; ++q) ob[q] = zv[q];
    }
}

extern "C" void kernel_launch(void* const* d_in, const int* in_sizes, int n_in,
                              void* d_out, int out_size, void* d_ws, size_t ws_size,
                              hipStream_t stream) {
    const float* x     = (const float*)d_in[0];
    const float* prot  = (const float*)d_in[1];
    const float* penta = (const float*)d_in[2];
    float* out = (float*)d_out;
    const int B = in_sizes[0] / (4 * NQ);   // 4096
    qsim_kernel<<<B, NT, 0, stream>>>(x, prot, penta, out);
}

// Round 18
// 126.701 us; speedup vs baseline: 1.2846x; 1.2599x over previous
//
#include <hip/hip_runtime.h>
#include <math.h>

#define NQ   12
#define NL   4
#define NT   64
#define AMPS 64   // per-thread amplitudes; amp = (lane<<6) | j
// state bits 11..6 = lane bits 5..0 (wires 0..5); state bits 5..0 = j bits 5..0 (wires 6..11)

typedef float cplx __attribute__((ext_vector_type(2)));   // VGPR pair for VOP3P

// ---- fused complex pair-op: u = Mx*s + My*p, exactly 4 VOP3P instrs (R10/R11-validated)
__device__ __forceinline__ cplx cpair(cplx Mx, cplx s, cplx My, cplx p) {
    cplx u;
    asm("v_pk_mul_f32 %0, %1, %2 op_sel:[0,0] op_sel_hi:[0,1]\n\t"
        "v_pk_fma_f32 %0, %1, %2, %0 op_sel:[1,1,0] op_sel_hi:[1,0,1] neg_lo:[1,0,0]\n\t"
        "v_pk_fma_f32 %0, %3, %4, %0 op_sel:[0,0,0] op_sel_hi:[0,1,1]\n\t"
        "v_pk_fma_f32 %0, %3, %4, %0 op_sel:[1,1,0] op_sel_hi:[1,0,1] neg_lo:[1,0,0]"
        : "=&v"(u) : "v"(Mx), "v"(s), "v"(My), "v"(p));
    return u;
}
// u = a*b (complex), 2 instrs (R9-validated)
__device__ __forceinline__ cplx pk_cmul(cplx a, cplx b) {
    cplx u;
    asm("v_pk_mul_f32 %0, %1, %2 op_sel:[0,0] op_sel_hi:[0,1]\n\t"
        "v_pk_fma_f32 %0, %1, %2, %0 op_sel:[1,1,0] op_sel_hi:[1,0,1] neg_lo:[1,0,0]"
        : "=&v"(u) : "v"(a), "v"(b));
    return u;
}

// C = A * B (2x2 complex, row-major m00 m01 m10 m11)
__device__ __forceinline__ void mm2(const cplx* A, const cplx* B, cplx* C) {
    C[0] = cpair(A[0], B[0], A[1], B[2]);
    C[1] = cpair(A[0], B[1], A[1], B[3]);
    C[2] = cpair(A[2], B[0], A[3], B[2]);
    C[3] = cpair(A[2], B[1], A[3], B[3]);
}
// PennyLane Rot(phi, theta, omega) = RZ(omega) RY(theta) RZ(phi)
__device__ __forceinline__ void rotmat(float phi, float th, float om, cplx* M) {
    float ct, st_, ca, sa, cd, sd;
    sincosf(0.5f * th, &st_, &ct);
    sincosf(0.5f * (phi + om), &sa, &ca);
    sincosf(0.5f * (phi - om), &sd, &cd);
    M[0] = cplx{ct * ca, -ct * sa};
    M[1] = cplx{-st_ * cd, -st_ * sd};
    M[2] = cplx{st_ * cd, -st_ * sd};
    M[3] = cplx{ct * ca, ct * sa};
}
__device__ __forceinline__ void rowsel(const cplx* M, bool hi, cplx& Mx, cplx& My) {
    Mx = hi ? M[3] : M[0];
    My = hi ? M[2] : M[1];
}

// ---- cross-lane partner fetch for xor mask XM (all primitives R9/R10/R11-validated)
// xor1/2: DPP quad_perm. xor8: row_ror:8. xor4/16/32: __shfl_xor (DS pipe).
template<int CTRL>
__device__ __forceinline__ float dpp_perm(float v) {
    return __int_as_float(__builtin_amdgcn_update_dpp(
        __float_as_int(v), __float_as_int(v), CTRL, 0xF, 0xF, false));
}
template<int XM>
__device__ __forceinline__ float partner(float v) {
    if constexpr (XM == 8)      return dpp_perm<0x128>(v);   // row_ror:8
    else if constexpr (XM == 2) return dpp_perm<0x4E>(v);    // quad_perm [2,3,0,1]
    else if constexpr (XM == 1) return dpp_perm<0xB1>(v);    // quad_perm [1,0,3,2]
    else                        return __shfl_xor(v, XM, 64);
}
template<int XM>
__device__ __forceinline__ cplx partner_c(cplx v) {
    cplx p;
    p.x = partner<XM>(v.x);
    p.y = partner<XM>(v.y);
    return p;
}

// gate on a LANE target bit (xor mask XM); per-thread (Mx,My) pre-selected.
template<int XM>
__device__ __forceinline__ void lane_gate(cplx* s, cplx Mx, cplx My) {
    #pragma unroll
    for (int j0 = 0; j0 < AMPS; j0 += 4) {
        cplx pv[4];
        #pragma unroll
        for (int j = 0; j < 4; ++j) {
            pv[j].x = partner<XM>(s[j0 + j].x);
            pv[j].y = partner<XM>(s[j0 + j].y);
        }
        #pragma unroll
        for (int j = 0; j < 4; ++j)
            s[j0 + j] = cpair(Mx, s[j0 + j], My, pv[j]);
    }
}
// full 2x2 gate on LOCAL bit K, uniform matrix (per-thread)
template<int K>
__device__ __forceinline__ void local_gate(cplx* s, cplx M0, cplx M1, cplx M2, cplx M3) {
    #pragma unroll
    for (int j = 0; j < AMPS; ++j) {
        if ((j >> K) & 1) continue;
        const int i1 = j | (1 << K);
        cplx v0 = s[j], v1 = s[i1];
        s[j]  = cpair(M0, v0, M1, v1);
        s[i1] = cpair(M2, v0, M3, v1);
    }
}
// controlled pair-gate: control LOCAL bit CB selects A (c=0) or B (c=1), target LOCAL bit TB
template<int CB, int TB>
__device__ __forceinline__ void cgate_local(cplx* s, const cplx* A, const cplx* B) {
    cplx A0 = A[0], A1 = A[1], A2 = A[2], A3 = A[3];
    cplx B0 = B[0], B1 = B[1], B2 = B[2], B3 = B[3];
    #pragma unroll
    for (int j = 0; j < AMPS; ++j) {
        if ((j >> TB) & 1) continue;
        const int i1 = j | (1 << TB);
        cplx v0 = s[j], v1 = s[i1];
        if ((j >> CB) & 1) {
            s[j]  = cpair(B0, v0, B1, v1);
            s[i1] = cpair(B2, v0, B3, v1);
        } else {
            s[j]  = cpair(A0, v0, A1, v1);
            s[i1] = cpair(A2, v0, A3, v1);
        }
    }
}

// ---- layer-0 factorized helpers ----
// prefix gate: c/t are lane bits of the SAMPLE state; B branch only (A=I)
template<int XM>
__device__ __forceinline__ cplx pref_gate(cplx lp, const cplx* Bm, bool cbit, bool tbit) {
    cplx Mx, My; rowsel(Bm, tbit, Mx, My);
    cplx p = partner_c<XM>(lp);
    cplx nl = cpair(Mx, lp, My, p);
    return cbit ? nl : lp;
}
// table gate: c/t are table-lane bits (wires 6..11); B branch only (A=I)
template<int XM>
__device__ __forceinline__ cplx tab_gate(cplx t, const cplx* Bm, bool cbit, bool tbit) {
    cplx Mx, My; rowsel(Bm, tbit, Mx, My);
    cplx p = partner_c<XM>(t);
    cplx nt = cpair(Mx, t, My, p);
    return cbit ? nt : t;
}

__global__ __launch_bounds__(NT, 1) void qsim_kernel(
    const float* __restrict__ x,      // (B, 4, NQ)
    const float* __restrict__ prot,   // (NL, NQ, 3)
    const float* __restrict__ penta,  // (NL, NQ, 3)
    float* __restrict__ out)          // (B, NQ)
{
    __shared__ cplx xbuf[640];        // setup scratch: ENC/RM/EM/UU
    __shared__ cplx GA[NL * NQ][4];   // c=0 branch (persistent)
    __shared__ cplx GB[NL * NQ][4];   // c=1 branch (persistent)
    __shared__ cplx ltab2[2][AMPS];   // layer-0 tables (c(wire5)=0 and =1 variants)

    cplx* ENCp = xbuf;                // 48
    cplx* RMp  = xbuf + 48;           // 192
    cplx* EMp  = xbuf + 240;          // 192
    cplx* UUp  = xbuf + 432;          // 192 (ends at 624)

    const int tid = threadIdx.x;      // == lane, 0..63
    const int b   = blockIdx.x;

    // ---- per-sample fused encoding: ENC = RY(x3) RZ(x2) RX(x1) RY(x0)
    if (tid < NQ) {
        const int q = tid;
        const float* xb = x + (size_t)b * 4 * NQ;
        const float t0 = xb[q], t1 = xb[NQ + q], t2 = xb[2 * NQ + q], t3 = xb[3 * NQ + q];
        float c, s;
        sincosf(0.5f * t0, &s, &c);
        cplx R0[4] = {cplx{c, 0.f}, cplx{-s, 0.f}, cplx{s, 0.f}, cplx{c, 0.f}};   // RY
        sincosf(0.5f * t1, &s, &c);
        cplx R1[4] = {cplx{c, 0.f}, cplx{0.f, -s}, cplx{0.f, -s}, cplx{c, 0.f}};  // RX
        sincosf(0.5f * t2, &s, &c);
        cplx R2[4] = {cplx{c, -s}, cplx{0.f, 0.f}, cplx{0.f, 0.f}, cplx{c, s}};   // RZ
        sincosf(0.5f * t3, &s, &c);
        cplx R3[4] = {cplx{c, 0.f}, cplx{-s, 0.f}, cplx{s, 0.f}, cplx{c, 0.f}};   // RY
        cplx T1[4], T2[4], E[4];
        mm2(R1, R0, T1);
        mm2(R2, T1, T2);
        mm2(R3, T2, E);
        #pragma unroll
        for (int i = 0; i < 4; ++i) ENCp[q * 4 + i] = E[i];
    }
    if (tid < NL * NQ) {
        cplx M[4];
        rotmat(prot[3 * tid], prot[3 * tid + 1], prot[3 * tid + 2], M);
        #pragma unroll
        for (int i = 0; i < 4; ++i) RMp[tid * 4 + i] = M[i];
        rotmat(penta[3 * tid], penta[3 * tid + 1], penta[3 * tid + 2], M);
        #pragma unroll
        for (int i = 0; i < 4; ++i) EMp[tid * 4 + i] = M[i];
    }
    __syncthreads();
    if (tid < NL * NQ) {
        cplx U[4];
        mm2(RMp + tid * 4, ENCp + (tid % NQ) * 4, U);
        #pragma unroll
        for (int i = 0; i < 4; ++i) UUp[tid * 4 + i] = U[i];
    }
    __syncthreads();
    // ---- fused controlled-gate pairs (validated rounds 3-11):
    // q<11:  A = U_{q+1}(l) (I for l=0), B = EM * A
    // q==11: A = U_0(l+1)   (I for l=3), B = A * EM
    if (tid < NL * NQ) {
        const int l = tid / NQ, q = tid - l * NQ;
        cplx A[4], B[4];
        if (q < 11) {
            if (l == 0) { A[0] = cplx{1.f,0.f}; A[1] = cplx{0.f,0.f}; A[2] = cplx{0.f,0.f}; A[3] = cplx{1.f,0.f}; }
            else {
                #pragma unroll
                for (int i = 0; i < 4; ++i) A[i] = UUp[(l * NQ + q + 1) * 4 + i];
            }
            mm2(EMp + tid * 4, A, B);
        } else {
            if (l == NL - 1) { A[0] = cplx{1.f,0.f}; A[1] = cplx{0.f,0.f}; A[2] = cplx{0.f,0.f}; A[3] = cplx{1.f,0.f}; }
            else {
                #pragma unroll
                for (int i = 0; i < 4; ++i) A[i] = UUp[((l + 1) * NQ) * 4 + i];
            }
            mm2(A, EMp + tid * 4, B);
        }
        #pragma unroll
        for (int i = 0; i < 4; ++i) { GA[tid][i] = A[i]; GB[tid][i] = B[i]; }
    }
    __syncthreads();

    // ==== factorized init + ENTIRE LAYER 0 on the rank-1 factors ====
    // t0(j): product over wires 6..11 (this thread = table entry j=tid)
    cplx t0 = cplx{1.f, 0.f};
    #pragma unroll
    for (int wq = 6; wq < 12; ++wq) {
        const int bit = (tid >> (11 - wq)) & 1;
        t0 = pk_cmul(t0, bit ? UUp[wq * 4 + 2] : UUp[wq * 4 + 0]);
    }
    // lp(lane): product over wires 0..5
    cplx lp = cplx{1.f, 0.f};
    #pragma unroll
    for (int wq = 0; wq < 6; ++wq) {
        const int bit = (tid >> (5 - wq)) & 1;
        lp = pk_cmul(lp, bit ? UUp[wq * 4 + 2] : UUp[wq * 4 + 0]);
    }
    // layer-0 q=0..4: lane-space cgates (A=I, B=GB[q]) applied to lp
    lp = pref_gate<16>(lp, &GB[0][0], tid & 32, tid & 16);   // q0: c=b5, t=b4
    lp = pref_gate<8 >(lp, &GB[1][0], tid & 16, tid & 8);    // q1: c=b4, t=b3
    lp = pref_gate<4 >(lp, &GB[2][0], tid & 8,  tid & 4);    // q2: c=b3, t=b2
    lp = pref_gate<2 >(lp, &GB[3][0], tid & 4,  tid & 2);    // q3: c=b2, t=b1
    lp = pref_gate<1 >(lp, &GB[4][0], tid & 2,  tid & 1);    // q4: c=b1, t=b0
    // q5: c=wire5 (sample lane b0), t=wire6 (table b5): make the c=1 table
    cplx tB;
    {
        cplx Mx, My; rowsel(&GB[5][0], tid & 32, Mx, My);
        tB = cpair(Mx, t0, My, partner_c<32>(t0));
    }
    // q6..q10: table-space cgates (A=I) on BOTH tables
    t0 = tab_gate<16>(t0, &GB[6][0],  tid & 32, tid & 16);
    tB = tab_gate<16>(tB, &GB[6][0],  tid & 32, tid & 16);
    t0 = tab_gate<8 >(t0, &GB[7][0],  tid & 16, tid & 8);
    tB = tab_gate<8 >(tB, &GB[7][0],  tid & 16, tid & 8);
    t0 = tab_gate<4 >(t0, &GB[8][0],  tid & 8,  tid & 4);
    tB = tab_gate<4 >(tB, &GB[8][0],  tid & 8,  tid & 4);
    t0 = tab_gate<2 >(t0, &GB[9][0],  tid & 4,  tid & 2);
    tB = tab_gate<2 >(tB, &GB[9][0],  tid & 4,  tid & 2);
    t0 = tab_gate<1 >(t0, &GB[10][0], tid & 2,  tid & 1);
    tB = tab_gate<1 >(tB, &GB[10][0], tid & 2,  tid & 1);
    // q11: c=wire11 (j parity), t=wire0 (sample lane b5): split prefix into A/B branches
    cplx lpA, lpB;
    {
        cplx p = partner_c<32>(lp);
        cplx Mx, My;
        rowsel(&GA[11][0], tid & 32, Mx, My);
        lpA = cpair(Mx, lp, My, p);
        rowsel(&GB[11][0], tid & 32, Mx, My);
        lpB = cpair(Mx, lp, My, p);
    }
    // publish tables
    ltab2[0][tid] = t0;
    ltab2[1][tid] = tB;
    __syncthreads();

    // ---- init state (layer 0 fully applied): s[j] = pref(j&1) * T_{lane&1}[j]
    const cplx* T = ltab2[tid & 1];
    cplx s[AMPS];
    #pragma unroll
    for (int j = 0; j < AMPS; ++j)
        s[j] = pk_cmul((j & 1) ? lpB : lpA, T[j]);

    // ---- layers 1..3: 36 fused controlled-pair gates, ZERO barriers
    for (int l = 1; l < NL; ++l) {
        const int g = l * NQ;
        // q=0: c wire0 (lane bit5), t wire1 (lane bit4, xor16)
        {
            const cplx* M = (tid & 32) ? &GB[g + 0][0] : &GA[g + 0][0];
            cplx Mx, My; rowsel(M, tid & 16, Mx, My);
            lane_gate<16>(s, Mx, My);
        }
        // q=1: c lane4, t lane3 (xor8, DPP)
        {
            const cplx* M = (tid & 16) ? &GB[g + 1][0] : &GA[g + 1][0];
            cplx Mx, My; rowsel(M, tid & 8, Mx, My);
            lane_gate<8>(s, Mx, My);
        }
        // q=2: c lane3, t lane2 (xor4)
        {
            const cplx* M = (tid & 8) ? &GB[g + 2][0] : &GA[g + 2][0];
            cplx Mx, My; rowsel(M, tid & 4, Mx, My);
            lane_gate<4>(s, Mx, My);
        }
        // q=3: c lane2, t lane1 (xor2, DPP)
        {
            const cplx* M = (tid & 4) ? &GB[g + 3][0] : &GA[g + 3][0];
            cplx Mx, My; rowsel(M, tid & 2, Mx, My);
            lane_gate<2>(s, Mx, My);
        }
        // q=4: c lane1, t lane0 (xor1, DPP)
        {
            const cplx* M = (tid & 2) ? &GB[g + 4][0] : &GA[g + 4][0];
            cplx Mx, My; rowsel(M, tid & 1, Mx, My);
            lane_gate<1>(s, Mx, My);
        }
        // q=5: c lane0, t local bit5
        {
            const cplx* M = (tid & 1) ? &GB[g + 5][0] : &GA[g + 5][0];
            local_gate<5>(s, M[0], M[1], M[2], M[3]);
        }
        // q=6..10: both local
        cgate_local<5, 4>(s, &GA[g + 6][0], &GB[g + 6][0]);
        cgate_local<4, 3>(s, &GA[g + 7][0], &GB[g + 7][0]);
        cgate_local<3, 2>(s, &GA[g + 8][0], &GB[g + 8][0]);
        cgate_local<2, 1>(s, &GA[g + 9][0], &GB[g + 9][0]);
        cgate_local<1, 0>(s, &GA[g + 10][0], &GB[g + 10][0]);
        // q=11: c local bit0 (j parity), t wire0 (lane bit5) -> xor32 shuffle, per-amp A/B
        {
            cplx Ax, Ay, Bx, By;
            rowsel(&GA[g + 11][0], tid & 32, Ax, Ay);
            rowsel(&GB[g + 11][0], tid & 32, Bx, By);
            #pragma unroll
            for (int j0 = 0; j0 < AMPS; j0 += 4) {
                cplx pv[4];
                #pragma unroll
                for (int j = 0; j < 4; ++j) {
                    pv[j].x = __shfl_xor(s[j0 + j].x, 32, 64);
                    pv[j].y = __shfl_xor(s[j0 + j].y, 32, 64);
                }
                #pragma unroll
                for (int j = 0; j < 4; ++j) {
                    if ((j0 + j) & 1) s[j0 + j] = cpair(Bx, s[j0 + j], By, pv[j]);
                    else              s[j0 + j] = cpair(Ax, s[j0 + j], Ay, pv[j]);
                }
            }
        }
    }

    // ---- measurement: z_i over state bit (11-i); amp = (tid<<6)|j
    float psum = 0.f;
    float zl[6] = {0.f, 0.f, 0.f, 0.f, 0.f, 0.f};   // wires 6..11 (j bits 5..0)
    #pragma unroll
    for (int j = 0; j < AMPS; ++j) {
        cplx v = s[j];
        float pr = fmaf(v.x, v.x, v.y * v.y);
        psum += pr;
        int pb = __float_as_int(pr);
        #pragma unroll
        for (int i = 0; i < 6; ++i)
            zl[i] += __int_as_float(pb ^ (((j >> (5 - i)) & 1) << 31));
    }
    float zv[NQ];
    #pragma unroll
    for (int i = 0; i < 6; ++i)                      // wires 0..5: sign = lane bit (5-i)
        zv[i] = ((tid >> (5 - i)) & 1) ? -psum : psum;
    #pragma unroll
    for (int i = 0; i < 6; ++i) zv[6 + i] = zl[i];
    #pragma unroll
    for (int q = 0; q < NQ; ++q) {
        float v = zv[q];
        #pragma unroll
        for (int off = 32; off > 0; off >>= 1) v += __shfl_xor(v, off, 64);
        zv[q] = v;
    }
    if (tid == 0) {
        float* ob = out + (size_t)b * NQ;
        #pragma unroll
        for (int q = 0; q < NQ; ++q) ob[q] = zv[q];
    }
}

extern "C" void kernel_launch(void* const* d_in, const int* in_sizes, int n_in,
                              void* d_out, int out_size, void* d_ws, size_t ws_size,
                              hipStream_t stream) {
    const float* x     = (const float*)d_in[0];
    const float* prot  = (const float*)d_in[1];
    const float* penta = (const float*)d_in[2];
    float* out = (float*)d_out;
    const int B = in_sizes[0] / (4 * NQ);   // 4096
    qsim_kernel<<<B, NT, 0, stream>>>(x, prot, penta, out);
}